// Round 1
// baseline (322.571 us; speedup 1.0000x reference)
//
#include <hip/hip_runtime.h>

typedef unsigned short ushort_t;
typedef unsigned int uint_t;
typedef unsigned long long u64;
typedef __attribute__((ext_vector_type(8))) short bf16x8;
typedef __attribute__((ext_vector_type(4))) float f32x4;

#define B_ 8
#define L_ 1024
#define C_ 768
#define H_ 6
#define D_ 128
#define BH_ 48
#define NEGINF (-1e9f)

// round-to-nearest-even f32 -> bf16 (no NaN handling needed; data is finite)
__device__ __forceinline__ ushort_t f2bf(float f) {
  uint_t u = __builtin_bit_cast(uint_t, f);
  u += 0x7fffu + ((u >> 16) & 1u);
  return (ushort_t)(u >> 16);
}

// ---------------------------------------------------------------- converts
__global__ void cvt_f32_bf16(const float* __restrict__ in, ushort_t* __restrict__ out, int n8) {
  int i = blockIdx.x * 256 + threadIdx.x;
  if (i >= n8) return;
  const float4* p = (const float4*)in + (size_t)i * 2;
  float4 a = p[0], b = p[1];
  uint4 r;
  r.x = (uint_t)f2bf(a.x) | ((uint_t)f2bf(a.y) << 16);
  r.y = (uint_t)f2bf(a.z) | ((uint_t)f2bf(a.w) << 16);
  r.z = (uint_t)f2bf(b.x) | ((uint_t)f2bf(b.y) << 16);
  r.w = (uint_t)f2bf(b.z) | ((uint_t)f2bf(b.w) << 16);
  ((uint4*)out)[i] = r;
}

// ------------------------------------------------- bit-pack a1 / d<=2 / d<=3
__global__ __launch_bounds__(256)
void pack_masks(const int* __restrict__ adj, const int* __restrict__ dist,
                u64* __restrict__ a1p, u64* __restrict__ d2p, u64* __restrict__ d3p) {
  int l = blockIdx.x, b = blockIdx.y, t = threadIdx.x;
  size_t base = ((size_t)b * L_ + l) * L_;
  size_t rb = ((size_t)b * L_ + l) * 16;
  #pragma unroll
  for (int it = 0; it < 4; ++it) {
    int c = it * 256 + t;
    int av = adj[base + c];
    int dv = dist[base + c];
    u64 m1 = __ballot((av > 0) || (c == l));
    u64 m2 = __ballot(dv <= 2);
    u64 m3 = __ballot(dv <= 3);
    if ((t & 63) == 0) {
      int w = it * 4 + (t >> 6);
      a1p[rb + w] = m1; d2p[rb + w] = m2; d3p[rb + w] = m3;
    }
  }
}

// ------------------------------------------------- 2-hop closure (bit OR)
__global__ __launch_bounds__(256)
void hop2(const u64* __restrict__ a1p, u64* __restrict__ a2p) {
  int tid = blockIdx.x * 256 + threadIdx.x;   // 0..8191 = (b,l)
  int b = tid >> 10;
  size_t rb = (size_t)tid * 16;
  u64 row[16], acc[16];
  #pragma unroll
  for (int j = 0; j < 16; ++j) { row[j] = a1p[rb + j]; acc[j] = 0ULL; }
  bool done = false;
  #pragma unroll
  for (int mw = 0; mw < 16; ++mw) {
    if (done) continue;
    u64 bits = row[mw];
    while (bits) {
      int tz = __builtin_ctzll(bits); bits &= bits - 1;
      const u64* src = a1p + (((size_t)b << 10) + (mw << 6) + tz) * 16;
      u64 band = ~0ULL;
      #pragma unroll
      for (int j = 0; j < 16; ++j) { acc[j] |= src[j]; band &= acc[j]; }
      if (band == ~0ULL) { done = true; break; }
    }
  }
  #pragma unroll
  for (int j = 0; j < 16; ++j) a2p[rb + j] = acc[j];
}

// ------------------------------------------------- bf16 GEMM  C = A @ B^T
// A: [M][K] bf16, B: [N][K] bf16.  128x128 tile, BK=32, 4 waves (2x2 of 64x64).
// EPI 0: qkv epilogue -> q(scaled) [bh][l][d], k [bh][l][d], vT [bh][d][l]
// EPI 1: fp32 store to fo[r*N + c]
template<int EPI>
__global__ __launch_bounds__(256)
void gemm_bt(const ushort_t* __restrict__ A, const ushort_t* __restrict__ Bm,
             int N, int K,
             ushort_t* __restrict__ qo, ushort_t* __restrict__ ko,
             ushort_t* __restrict__ vTo, float* __restrict__ fo) {
  __shared__ __align__(16) ushort_t As[128 * 32];
  __shared__ __align__(16) ushort_t Bs[128 * 32];
  int t = threadIdx.x;
  int lane = t & 63, lo = lane & 15, hi = lane >> 4;
  int wv = t >> 6, wm = wv >> 1, wn = wv & 1;
  int m0 = blockIdx.y * 128, n0 = blockIdx.x * 128;

  f32x4 acc[4][4];
  #pragma unroll
  for (int mi = 0; mi < 4; ++mi)
    #pragma unroll
    for (int ni = 0; ni < 4; ++ni) acc[mi][ni] = (f32x4){0.f, 0.f, 0.f, 0.f};

  for (int kt = 0; kt < K; kt += 32) {
    int u0 = t, u1 = t + 256;
    const ushort_t* ga0 = A + ((size_t)(m0 + (u0 >> 2)) * K + kt + (u0 & 3) * 8);
    const ushort_t* ga1 = A + ((size_t)(m0 + (u1 >> 2)) * K + kt + (u1 & 3) * 8);
    const ushort_t* gb0 = Bm + ((size_t)(n0 + (u0 >> 2)) * K + kt + (u0 & 3) * 8);
    const ushort_t* gb1 = Bm + ((size_t)(n0 + (u1 >> 2)) * K + kt + (u1 & 3) * 8);
    __builtin_amdgcn_global_load_lds((const __attribute__((address_space(1))) void*)ga0,
        (__attribute__((address_space(3))) void*)&As[(size_t)u0 * 8], 16, 0, 0);
    __builtin_amdgcn_global_load_lds((const __attribute__((address_space(1))) void*)ga1,
        (__attribute__((address_space(3))) void*)&As[(size_t)u1 * 8], 16, 0, 0);
    __builtin_amdgcn_global_load_lds((const __attribute__((address_space(1))) void*)gb0,
        (__attribute__((address_space(3))) void*)&Bs[(size_t)u0 * 8], 16, 0, 0);
    __builtin_amdgcn_global_load_lds((const __attribute__((address_space(1))) void*)gb1,
        (__attribute__((address_space(3))) void*)&Bs[(size_t)u1 * 8], 16, 0, 0);
    __syncthreads();
    bf16x8 af[4], bfr[4];
    #pragma unroll
    for (int mi = 0; mi < 4; ++mi)
      af[mi] = *(const bf16x8*)&As[(wm * 64 + mi * 16 + lo) * 32 + hi * 8];
    #pragma unroll
    for (int ni = 0; ni < 4; ++ni)
      bfr[ni] = *(const bf16x8*)&Bs[(wn * 64 + ni * 16 + lo) * 32 + hi * 8];
    #pragma unroll
    for (int mi = 0; mi < 4; ++mi)
      #pragma unroll
      for (int ni = 0; ni < 4; ++ni)
        acc[mi][ni] = __builtin_amdgcn_mfma_f32_16x16x32_bf16(af[mi], bfr[ni], acc[mi][ni], 0, 0, 0);
    __syncthreads();
  }

  // epilogue. D layout: col = lane&15, row = (lane>>4)*4 + j  [m89-verified]
  #pragma unroll
  for (int mi = 0; mi < 4; ++mi) {
    int rbase = m0 + wm * 64 + mi * 16 + hi * 4;
    #pragma unroll
    for (int ni = 0; ni < 4; ++ni) {
      int c = n0 + wn * 64 + ni * 16 + lo;
      f32x4 v = acc[mi][ni];
      if (EPI == 0) {
        int sec = c / 768;
        int cc = c - sec * 768;
        int h = cc >> 7, dd = cc & 127;
        #pragma unroll
        for (int j = 0; j < 4; ++j) {
          int r = rbase + j;
          int b = r >> 10, l = r & 1023;
          size_t bh = (size_t)(b * H_ + h);
          if (sec == 0)      qo[(bh * L_ + l) * D_ + dd] = f2bf(v[j] * 0.08838834764831845f);
          else if (sec == 1) ko[(bh * L_ + l) * D_ + dd] = f2bf(v[j]);
          else               vTo[(bh * D_ + dd) * L_ + l] = f2bf(v[j]);
        }
      } else {
        #pragma unroll
        for (int j = 0; j < 4; ++j)
          fo[(size_t)(rbase + j) * N + c] = v[j];
      }
    }
  }
}

// ------------------------------------------------- flash attention w/ masks
// 1 wave per block; 16 q-rows per block; online softmax over 16 chunks of 64.
__global__ __launch_bounds__(64)
void attn_kernel(const ushort_t* __restrict__ q, const ushort_t* __restrict__ k,
                 const ushort_t* __restrict__ vT, ushort_t* __restrict__ obf,
                 const u64* __restrict__ a1p, const u64* __restrict__ a2p,
                 const u64* __restrict__ d2p, const u64* __restrict__ d3p) {
  __shared__ __align__(16) ushort_t Plds[16 * 64];
  int lane = threadIdx.x, lo = lane & 15, hi = lane >> 4;
  int qt = blockIdx.x, bh = blockIdx.y;
  int b = bh / H_, h = bh - b * H_;
  int qbase = qt * 16;
  const ushort_t* qp = q + ((size_t)bh * L_ + qbase) * D_;
  const ushort_t* kp = k + (size_t)bh * L_ * D_;
  const ushort_t* vp = vT + (size_t)bh * D_ * L_;

  bf16x8 aq[4];
  #pragma unroll
  for (int kk = 0; kk < 4; ++kk)
    aq[kk] = *(const bf16x8*)(qp + (size_t)lo * D_ + kk * 32 + hi * 8);

  const u64* mp = (h == 1) ? a1p : (h == 2) ? a2p : (h == 3) ? d2p : (h == 4) ? d3p : nullptr;
  int mode = (h == 0) ? 0 : (h == 5) ? 2 : 1;   // 0=eye, 1=packed, 2=full

  float m_run[4], l_run[4];
  f32x4 acc_o[8];
  #pragma unroll
  for (int j = 0; j < 4; ++j) { m_run[j] = NEGINF; l_run[j] = 0.f; }
  #pragma unroll
  for (int nt = 0; nt < 8; ++nt) acc_o[nt] = (f32x4){0.f, 0.f, 0.f, 0.f};

  for (int ch = 0; ch < 16; ++ch) {
    int kc0 = ch * 64;
    u64 wmj[4];
    if (mode == 1) {
      #pragma unroll
      for (int j = 0; j < 4; ++j)
        wmj[j] = mp[((size_t)b * L_ + qbase + hi * 4 + j) * 16 + ch];
    }
    // S tile: rows hi*4+j, cols kc0 + st*16 + lo
    float sv[4][4];
    #pragma unroll
    for (int st = 0; st < 4; ++st) {
      f32x4 s = (f32x4){0.f, 0.f, 0.f, 0.f};
      #pragma unroll
      for (int kk = 0; kk < 4; ++kk) {
        bf16x8 bk = *(const bf16x8*)(kp + (size_t)(kc0 + st * 16 + lo) * D_ + kk * 32 + hi * 8);
        s = __builtin_amdgcn_mfma_f32_16x16x32_bf16(aq[kk], bk, s, 0, 0, 0);
      }
      #pragma unroll
      for (int j = 0; j < 4; ++j) {
        bool bit;
        if (mode == 0)      bit = (qbase + hi * 4 + j) == (kc0 + st * 16 + lo);
        else if (mode == 2) bit = true;
        else                bit = (wmj[j] >> (st * 16 + lo)) & 1ULL;
        sv[st][j] = bit ? s[j] : NEGINF;
      }
    }
    // online softmax update per row j
    float corr[4], pv[4][4];
    #pragma unroll
    for (int j = 0; j < 4; ++j) {
      float mx = fmaxf(fmaxf(sv[0][j], sv[1][j]), fmaxf(sv[2][j], sv[3][j]));
      #pragma unroll
      for (int o = 8; o >= 1; o >>= 1) mx = fmaxf(mx, __shfl_xor(mx, o, 16));
      float mn = fmaxf(m_run[j], mx);
      corr[j] = __expf(m_run[j] - mn);
      float rs = 0.f;
      #pragma unroll
      for (int st = 0; st < 4; ++st) { float pp = __expf(sv[st][j] - mn); pv[st][j] = pp; rs += pp; }
      #pragma unroll
      for (int o = 8; o >= 1; o >>= 1) rs += __shfl_xor(rs, o, 16);
      l_run[j] = l_run[j] * corr[j] + rs;
      m_run[j] = mn;
    }
    f32x4 corrv = (f32x4){corr[0], corr[1], corr[2], corr[3]};
    #pragma unroll
    for (int nt = 0; nt < 8; ++nt) acc_o[nt] *= corrv;
    // P -> LDS (D-layout write, A-frag read)
    #pragma unroll
    for (int st = 0; st < 4; ++st)
      #pragma unroll
      for (int j = 0; j < 4; ++j)
        Plds[(hi * 4 + j) * 64 + st * 16 + lo] = f2bf(pv[st][j]);
    __syncthreads();
    bf16x8 pa[2];
    #pragma unroll
    for (int kk2 = 0; kk2 < 2; ++kk2)
      pa[kk2] = *(const bf16x8*)&Plds[lo * 64 + kk2 * 32 + hi * 8];
    #pragma unroll
    for (int nt = 0; nt < 8; ++nt) {
      #pragma unroll
      for (int kk2 = 0; kk2 < 2; ++kk2) {
        bf16x8 bv = *(const bf16x8*)(vp + (size_t)(nt * 16 + lo) * L_ + kc0 + kk2 * 32 + hi * 8);
        acc_o[nt] = __builtin_amdgcn_mfma_f32_16x16x32_bf16(pa[kk2], bv, acc_o[nt], 0, 0, 0);
      }
    }
    __syncthreads();
  }
  // epilogue: O /= l, write bf16 [b][l][h*128+dd]
  float inv[4];
  #pragma unroll
  for (int j = 0; j < 4; ++j) inv[j] = 1.f / l_run[j];
  #pragma unroll
  for (int nt = 0; nt < 8; ++nt)
    #pragma unroll
    for (int j = 0; j < 4; ++j)
      obf[((size_t)b * L_ + qbase + hi * 4 + j) * C_ + h * D_ + nt * 16 + lo] =
          f2bf(acc_o[nt][j] * inv[j]);
}

// ---------------------------------------------------------------- launcher
extern "C" void kernel_launch(void* const* d_in, const int* in_sizes, int n_in,
                              void* d_out, int out_size, void* d_ws, size_t ws_size,
                              hipStream_t stream) {
  const float* x     = (const float*)d_in[0];
  const int*   adj   = (const int*)d_in[1];
  const int*   dist  = (const int*)d_in[2];
  const float* wqkv  = (const float*)d_in[3];
  const float* wproj = (const float*)d_in[4];
  float* out = (float*)d_out;
  char* ws = (char*)d_ws;

  // workspace layout (bytes)
  const size_t SZ_X   = (size_t)B_ * L_ * C_ * 2;        // 12.6 MB
  const size_t SZ_WQ  = (size_t)3 * C_ * C_ * 2;         // 3.5 MB
  const size_t SZ_WP  = (size_t)C_ * C_ * 2;             // 1.2 MB
  const size_t SZ_QKV = (size_t)BH_ * L_ * D_ * 2;       // 12.6 MB each
  const size_t SZ_MSK = (size_t)B_ * L_ * 16 * 8;        // 1 MB each
  size_t off = 0;
  ushort_t* xbf  = (ushort_t*)(ws + off); off += SZ_X;
  ushort_t* wqb  = (ushort_t*)(ws + off); off += SZ_WQ;
  ushort_t* wpb  = (ushort_t*)(ws + off); off += SZ_WP;
  ushort_t* qb   = (ushort_t*)(ws + off); off += SZ_QKV;
  ushort_t* kb   = (ushort_t*)(ws + off); off += SZ_QKV;
  ushort_t* vTb  = (ushort_t*)(ws + off); off += SZ_QKV;
  ushort_t* ob   = (ushort_t*)(ws + off); off += SZ_QKV * 6 / H_ * (H_ / 6); off += 0; // == SZ_X
  off = (char*)ob - ws + SZ_X;
  u64* a1p = (u64*)(ws + off); off += SZ_MSK;
  u64* a2p = (u64*)(ws + off); off += SZ_MSK;
  u64* d2p = (u64*)(ws + off); off += SZ_MSK;
  u64* d3p = (u64*)(ws + off); off += SZ_MSK;
  (void)ws_size; (void)n_in; (void)in_sizes; (void)out_size;

  // converts
  cvt_f32_bf16<<<(B_ * L_ * C_ / 8 + 255) / 256, 256, 0, stream>>>(x, xbf, B_ * L_ * C_ / 8);
  cvt_f32_bf16<<<(3 * C_ * C_ / 8 + 255) / 256, 256, 0, stream>>>(wqkv, wqb, 3 * C_ * C_ / 8);
  cvt_f32_bf16<<<(C_ * C_ / 8 + 255) / 256, 256, 0, stream>>>(wproj, wpb, C_ * C_ / 8);
  // masks
  pack_masks<<<dim3(L_, B_), 256, 0, stream>>>(adj, dist, a1p, d2p, d3p);
  hop2<<<B_ * L_ / 256, 256, 0, stream>>>(a1p, a2p);
  // qkv = x @ wqkv^T  (M=8192, N=2304, K=768)
  gemm_bt<0><<<dim3(3 * C_ / 128, B_ * L_ / 128), 256, 0, stream>>>(
      xbf, wqb, 3 * C_, C_, qb, kb, vTb, nullptr);
  // attention
  attn_kernel<<<dim3(L_ / 16, BH_), 64, 0, stream>>>(qb, kb, vTb, ob, a1p, a2p, d2p, d3p);
  // out = O @ wproj^T  (M=8192, N=768, K=768)
  gemm_bt<1><<<dim3(C_ / 128, B_ * L_ / 128), 256, 0, stream>>>(
      ob, wpb, C_, C_, nullptr, nullptr, nullptr, out);
}

// Round 2
// 231.989 us; speedup vs baseline: 1.3905x; 1.3905x over previous
//
#include <hip/hip_runtime.h>

typedef unsigned short ushort_t;
typedef unsigned int uint_t;
typedef unsigned long long u64;
typedef __attribute__((ext_vector_type(8))) short bf16x8;
typedef __attribute__((ext_vector_type(4))) float f32x4;

#define B_ 8
#define L_ 1024
#define C_ 768
#define H_ 6
#define D_ 128
#define BH_ 48
#define NEGINF (-1e9f)

#define AS1 __attribute__((address_space(1)))
#define AS3 __attribute__((address_space(3)))

// round-to-nearest-even f32 -> bf16
__device__ __forceinline__ ushort_t f2bf(float f) {
  uint_t u = __builtin_bit_cast(uint_t, f);
  u += 0x7fffu + ((u >> 16) & 1u);
  return (ushort_t)(u >> 16);
}

// ---------------------------------------------------------------- converts
__global__ void cvt_f32_bf16(const float* __restrict__ in, ushort_t* __restrict__ out, int n8) {
  int i = blockIdx.x * 256 + threadIdx.x;
  if (i >= n8) return;
  const float4* p = (const float4*)in + (size_t)i * 2;
  float4 a = p[0], b = p[1];
  uint4 r;
  r.x = (uint_t)f2bf(a.x) | ((uint_t)f2bf(a.y) << 16);
  r.y = (uint_t)f2bf(a.z) | ((uint_t)f2bf(a.w) << 16);
  r.z = (uint_t)f2bf(b.x) | ((uint_t)f2bf(b.y) << 16);
  r.w = (uint_t)f2bf(b.z) | ((uint_t)f2bf(b.w) << 16);
  ((uint4*)out)[i] = r;
}

// ------------------------------------------------- bit-pack a1 / d<=2 / d<=3
__global__ __launch_bounds__(256)
void pack_masks(const int* __restrict__ adj, const int* __restrict__ dist,
                u64* __restrict__ a1p, u64* __restrict__ d2p, u64* __restrict__ d3p) {
  int l = blockIdx.x, b = blockIdx.y, t = threadIdx.x;
  size_t base = ((size_t)b * L_ + l) * L_;
  size_t rb = ((size_t)b * L_ + l) * 16;
  #pragma unroll
  for (int it = 0; it < 4; ++it) {
    int c = it * 256 + t;
    int av = adj[base + c];
    int dv = dist[base + c];
    u64 m1 = __ballot((av > 0) || (c == l));
    u64 m2 = __ballot(dv <= 2);
    u64 m3 = __ballot(dv <= 3);
    if ((t & 63) == 0) {
      int w = it * 4 + (t >> 6);
      a1p[rb + w] = m1; d2p[rb + w] = m2; d3p[rb + w] = m3;
    }
  }
}

// ------------------------------------------------- 2-hop closure (bit OR)
__global__ __launch_bounds__(256)
void hop2(const u64* __restrict__ a1p, u64* __restrict__ a2p) {
  int tid = blockIdx.x * 256 + threadIdx.x;   // 0..8191 = (b,l)
  int b = tid >> 10;
  size_t rb = (size_t)tid * 16;
  u64 row[16], acc[16];
  #pragma unroll
  for (int j = 0; j < 16; ++j) { row[j] = a1p[rb + j]; acc[j] = 0ULL; }
  bool done = false;
  #pragma unroll
  for (int mw = 0; mw < 16; ++mw) {
    if (done) continue;
    u64 bits = row[mw];
    while (bits) {
      int tz = __builtin_ctzll(bits); bits &= bits - 1;
      const u64* src = a1p + (((size_t)b << 10) + (mw << 6) + tz) * 16;
      u64 band = ~0ULL;
      #pragma unroll
      for (int j = 0; j < 16; ++j) { acc[j] |= src[j]; band &= acc[j]; }
      if (band == ~0ULL) { done = true; break; }
    }
  }
  #pragma unroll
  for (int j = 0; j < 16; ++j) a2p[rb + j] = acc[j];
}

// ------------------------------------------------- bf16 GEMM  C = A @ B^T
template<int EPI>
__global__ __launch_bounds__(256)
void gemm_bt(const ushort_t* __restrict__ A, const ushort_t* __restrict__ Bm,
             int N, int K,
             ushort_t* __restrict__ qo, ushort_t* __restrict__ ko,
             ushort_t* __restrict__ vTo, ushort_t* __restrict__ vo,
             float* __restrict__ fo) {
  __shared__ __align__(16) ushort_t As[128 * 32];
  __shared__ __align__(16) ushort_t Bs[128 * 32];
  int t = threadIdx.x;
  int lane = t & 63, lo = lane & 15, hi = lane >> 4;
  int wv = t >> 6, wm = wv >> 1, wn = wv & 1;
  int m0 = blockIdx.y * 128, n0 = blockIdx.x * 128;

  f32x4 acc[4][4];
  #pragma unroll
  for (int mi = 0; mi < 4; ++mi)
    #pragma unroll
    for (int ni = 0; ni < 4; ++ni) acc[mi][ni] = (f32x4){0.f, 0.f, 0.f, 0.f};

  for (int kt = 0; kt < K; kt += 32) {
    int u0 = t, u1 = t + 256;
    const ushort_t* ga0 = A + ((size_t)(m0 + (u0 >> 2)) * K + kt + (u0 & 3) * 8);
    const ushort_t* ga1 = A + ((size_t)(m0 + (u1 >> 2)) * K + kt + (u1 & 3) * 8);
    const ushort_t* gb0 = Bm + ((size_t)(n0 + (u0 >> 2)) * K + kt + (u0 & 3) * 8);
    const ushort_t* gb1 = Bm + ((size_t)(n0 + (u1 >> 2)) * K + kt + (u1 & 3) * 8);
    __builtin_amdgcn_global_load_lds((const AS1 void*)ga0, (AS3 void*)&As[(size_t)u0 * 8], 16, 0, 0);
    __builtin_amdgcn_global_load_lds((const AS1 void*)ga1, (AS3 void*)&As[(size_t)u1 * 8], 16, 0, 0);
    __builtin_amdgcn_global_load_lds((const AS1 void*)gb0, (AS3 void*)&Bs[(size_t)u0 * 8], 16, 0, 0);
    __builtin_amdgcn_global_load_lds((const AS1 void*)gb1, (AS3 void*)&Bs[(size_t)u1 * 8], 16, 0, 0);
    __syncthreads();
    bf16x8 af[4], bfr[4];
    #pragma unroll
    for (int mi = 0; mi < 4; ++mi)
      af[mi] = *(const bf16x8*)&As[(wm * 64 + mi * 16 + lo) * 32 + hi * 8];
    #pragma unroll
    for (int ni = 0; ni < 4; ++ni)
      bfr[ni] = *(const bf16x8*)&Bs[(wn * 64 + ni * 16 + lo) * 32 + hi * 8];
    #pragma unroll
    for (int mi = 0; mi < 4; ++mi)
      #pragma unroll
      for (int ni = 0; ni < 4; ++ni)
        acc[mi][ni] = __builtin_amdgcn_mfma_f32_16x16x32_bf16(af[mi], bfr[ni], acc[mi][ni], 0, 0, 0);
    __syncthreads();
  }

  // epilogue. D layout: col = lane&15, row = (lane>>4)*4 + j  [m89-verified]
  #pragma unroll
  for (int mi = 0; mi < 4; ++mi) {
    int rbase = m0 + wm * 64 + mi * 16 + hi * 4;
    #pragma unroll
    for (int ni = 0; ni < 4; ++ni) {
      int c = n0 + wn * 64 + ni * 16 + lo;
      f32x4 v = acc[mi][ni];
      if (EPI == 0) {
        int sec = c / 768;
        int cc = c - sec * 768;
        int h = cc >> 7, dd = cc & 127;
        #pragma unroll
        for (int j = 0; j < 4; ++j) {
          int r = rbase + j;
          int b = r >> 10, l = r & 1023;
          size_t bh = (size_t)(b * H_ + h);
          if (sec == 0)      qo[(bh * L_ + l) * D_ + dd] = f2bf(v[j] * 0.08838834764831845f);
          else if (sec == 1) ko[(bh * L_ + l) * D_ + dd] = f2bf(v[j]);
          else {
            ushort_t bv = f2bf(v[j]);
            vTo[(bh * D_ + dd) * L_ + l] = bv;
            vo[(bh * L_ + l) * D_ + dd] = bv;
          }
        }
      } else {
        #pragma unroll
        for (int j = 0; j < 4; ++j)
          fo[(size_t)(rbase + j) * N + c] = v[j];
      }
    }
  }
}

// ------------------------------------------------- flash attention w/ masks
// 4 waves / block; 64 q-rows per block (16/wave); K,V chunk staged in LDS via
// global_load_lds with pre-swizzled global source (linear LDS dest, XOR-swz read).
__global__ __launch_bounds__(256)
void attn_kernel(const ushort_t* __restrict__ q, const ushort_t* __restrict__ k,
                 const ushort_t* __restrict__ vT, const ushort_t* __restrict__ v,
                 ushort_t* __restrict__ obf,
                 const u64* __restrict__ a1p, const u64* __restrict__ a2p,
                 const u64* __restrict__ d2p, const u64* __restrict__ d3p) {
  __shared__ __align__(16) ushort_t Ks[64 * 128];   // [krow][d]   swizzled 16B blocks
  __shared__ __align__(16) ushort_t Vs[128 * 64];   // [d][kcol]   swizzled 16B blocks
  __shared__ __align__(16) ushort_t Plds[4][16 * 64];
  int t = threadIdx.x;
  int lane = t & 63, lo = lane & 15, hi = lane >> 4, wv = t >> 6;
  int qt = blockIdx.x, bh = blockIdx.y;
  int b = bh / H_, h = bh - b * H_;
  int qbase = qt * 64;          // block's q range
  int qw = qbase + wv * 16;     // this wave's q range

  if (h == 0) {
    // eye mask: softmax over the single diagonal element -> out = v[l]
    const ushort_t* vp = v + ((size_t)bh * L_ + qbase) * D_;
    #pragma unroll
    for (int it = 0; it < 4; ++it) {
      int r = it * 16 + (t >> 4);
      int cpos = (t & 15) * 8;
      bf16x8 val = *(const bf16x8*)(vp + (size_t)r * D_ + cpos);
      *(bf16x8*)(obf + ((size_t)b * L_ + qbase + r) * C_ + cpos) = val; // h*D_ == 0
    }
    return;
  }

  const ushort_t* qp = q + ((size_t)bh * L_ + qw) * D_;
  const ushort_t* kp = k + (size_t)bh * L_ * D_;
  const ushort_t* vp = vT + (size_t)bh * D_ * L_;

  bf16x8 aq[4];
  #pragma unroll
  for (int kk = 0; kk < 4; ++kk)
    aq[kk] = *(const bf16x8*)(qp + (size_t)lo * D_ + kk * 32 + hi * 8);

  const u64* mp = (h == 1) ? a1p : (h == 2) ? a2p : (h == 3) ? d2p : d3p;
  bool full = (h == 5);

  float m_run[4], l_run[4];
  f32x4 acc_o[8];
  #pragma unroll
  for (int j = 0; j < 4; ++j) { m_run[j] = NEGINF; l_run[j] = 0.f; }
  #pragma unroll
  for (int nt = 0; nt < 8; ++nt) acc_o[nt] = (f32x4){0.f, 0.f, 0.f, 0.f};

  for (int ch = 0; ch < 16; ++ch) {
    int kc0 = ch * 64;
    // stage K chunk: 64 rows x 256B. linear LDS dest, source col16 ^= row&7
    #pragma unroll
    for (int i = 0; i < 4; ++i) {
      int u = i * 256 + t;
      int row = u >> 4, c16 = u & 15;
      int sc16 = c16 ^ (row & 7);
      __builtin_amdgcn_global_load_lds(
          (const AS1 void*)(kp + (size_t)(kc0 + row) * D_ + sc16 * 8),
          (AS3 void*)&Ks[(size_t)u * 8], 16, 0, 0);
    }
    // stage V chunk: 128 rows x 128B
    #pragma unroll
    for (int i = 0; i < 4; ++i) {
      int u = i * 256 + t;
      int row = u >> 3, c16 = u & 7;
      int sc16 = c16 ^ (row & 7);
      __builtin_amdgcn_global_load_lds(
          (const AS1 void*)(vp + (size_t)row * L_ + kc0 + sc16 * 8),
          (AS3 void*)&Vs[(size_t)u * 8], 16, 0, 0);
    }
    __syncthreads();

    u64 wmj[4];
    if (!full) {
      #pragma unroll
      for (int j = 0; j < 4; ++j)
        wmj[j] = mp[((size_t)b * L_ + qw + hi * 4 + j) * 16 + ch];
    }

    // S tile: rows qw+hi*4+j, cols kc0 + st*16 + lo
    float sv[4][4];
    #pragma unroll
    for (int st = 0; st < 4; ++st) {
      f32x4 s = (f32x4){0.f, 0.f, 0.f, 0.f};
      int krow = st * 16 + lo;
      #pragma unroll
      for (int kk = 0; kk < 4; ++kk) {
        int c16s = (kk * 4 + hi) ^ (krow & 7);
        bf16x8 bk = *(const bf16x8*)&Ks[krow * 128 + c16s * 8];
        s = __builtin_amdgcn_mfma_f32_16x16x32_bf16(aq[kk], bk, s, 0, 0, 0);
      }
      #pragma unroll
      for (int j = 0; j < 4; ++j) {
        bool bit = full || ((wmj[j] >> (st * 16 + lo)) & 1ULL);
        sv[st][j] = bit ? s[j] : NEGINF;
      }
    }
    // online softmax per row j
    float corr[4], pv[4][4];
    #pragma unroll
    for (int j = 0; j < 4; ++j) {
      float mx = fmaxf(fmaxf(sv[0][j], sv[1][j]), fmaxf(sv[2][j], sv[3][j]));
      #pragma unroll
      for (int o = 8; o >= 1; o >>= 1) mx = fmaxf(mx, __shfl_xor(mx, o, 16));
      float mn = fmaxf(m_run[j], mx);
      corr[j] = __expf(m_run[j] - mn);
      float rs = 0.f;
      #pragma unroll
      for (int st = 0; st < 4; ++st) { float pp = __expf(sv[st][j] - mn); pv[st][j] = pp; rs += pp; }
      #pragma unroll
      for (int o = 8; o >= 1; o >>= 1) rs += __shfl_xor(rs, o, 16);
      l_run[j] = l_run[j] * corr[j] + rs;
      m_run[j] = mn;
    }
    f32x4 corrv = (f32x4){corr[0], corr[1], corr[2], corr[3]};
    #pragma unroll
    for (int nt = 0; nt < 8; ++nt) acc_o[nt] *= corrv;

    // P -> per-wave LDS (XOR-swizzled), then read back as A-frags
    char* pb = (char*)&Plds[wv][0];
    #pragma unroll
    for (int st = 0; st < 4; ++st)
      #pragma unroll
      for (int j = 0; j < 4; ++j) {
        int prow = hi * 4 + j;
        int addr = (prow * 128 + (st * 16 + lo) * 2) ^ ((prow & 7) << 4);
        *(ushort_t*)(pb + addr) = f2bf(pv[st][j]);
      }
    bf16x8 pa[2];
    #pragma unroll
    for (int kk2 = 0; kk2 < 2; ++kk2) {
      int addr = lo * 128 + (((kk2 * 4 + hi) ^ (lo & 7)) * 16);
      pa[kk2] = *(const bf16x8*)(pb + addr);
    }
    #pragma unroll
    for (int nt = 0; nt < 8; ++nt) {
      #pragma unroll
      for (int kk2 = 0; kk2 < 2; ++kk2) {
        int vrow = nt * 16 + lo;
        int c16s = (kk2 * 4 + hi) ^ (vrow & 7);
        bf16x8 bv = *(const bf16x8*)&Vs[vrow * 64 + c16s * 8];
        acc_o[nt] = __builtin_amdgcn_mfma_f32_16x16x32_bf16(pa[kk2], bv, acc_o[nt], 0, 0, 0);
      }
    }
    __syncthreads();
  }
  // epilogue
  float inv[4];
  #pragma unroll
  for (int j = 0; j < 4; ++j) inv[j] = 1.f / l_run[j];
  #pragma unroll
  for (int nt = 0; nt < 8; ++nt)
    #pragma unroll
    for (int j = 0; j < 4; ++j)
      obf[((size_t)b * L_ + qw + hi * 4 + j) * C_ + h * D_ + nt * 16 + lo] =
          f2bf(acc_o[nt][j] * inv[j]);
}

// ---------------------------------------------------------------- launcher
extern "C" void kernel_launch(void* const* d_in, const int* in_sizes, int n_in,
                              void* d_out, int out_size, void* d_ws, size_t ws_size,
                              hipStream_t stream) {
  const float* x     = (const float*)d_in[0];
  const int*   adj   = (const int*)d_in[1];
  const int*   dist  = (const int*)d_in[2];
  const float* wqkv  = (const float*)d_in[3];
  const float* wproj = (const float*)d_in[4];
  float* out = (float*)d_out;
  char* ws = (char*)d_ws;

  const size_t SZ_X   = (size_t)B_ * L_ * C_ * 2;        // 12.6 MB
  const size_t SZ_WQ  = (size_t)3 * C_ * C_ * 2;
  const size_t SZ_WP  = (size_t)C_ * C_ * 2;
  const size_t SZ_QKV = (size_t)BH_ * L_ * D_ * 2;       // 12.6 MB
  const size_t SZ_MSK = (size_t)B_ * L_ * 16 * 8;        // 1 MB
  size_t off = 0;
  ushort_t* xbf  = (ushort_t*)(ws + off); off += SZ_X;
  ushort_t* wqb  = (ushort_t*)(ws + off); off += SZ_WQ;
  ushort_t* wpb  = (ushort_t*)(ws + off); off += SZ_WP;
  ushort_t* qb   = (ushort_t*)(ws + off); off += SZ_QKV;
  ushort_t* kb   = (ushort_t*)(ws + off); off += SZ_QKV;
  ushort_t* vTb  = (ushort_t*)(ws + off); off += SZ_QKV;
  ushort_t* vb   = (ushort_t*)(ws + off); off += SZ_QKV;
  ushort_t* ob   = (ushort_t*)(ws + off); off += SZ_X;
  u64* a1p = (u64*)(ws + off); off += SZ_MSK;
  u64* a2p = (u64*)(ws + off); off += SZ_MSK;
  u64* d2p = (u64*)(ws + off); off += SZ_MSK;
  u64* d3p = (u64*)(ws + off); off += SZ_MSK;
  (void)ws_size; (void)n_in; (void)in_sizes; (void)out_size;

  cvt_f32_bf16<<<(B_ * L_ * C_ / 8 + 255) / 256, 256, 0, stream>>>(x, xbf, B_ * L_ * C_ / 8);
  cvt_f32_bf16<<<(3 * C_ * C_ / 8 + 255) / 256, 256, 0, stream>>>(wqkv, wqb, 3 * C_ * C_ / 8);
  cvt_f32_bf16<<<(C_ * C_ / 8 + 255) / 256, 256, 0, stream>>>(wproj, wpb, C_ * C_ / 8);
  pack_masks<<<dim3(L_, B_), 256, 0, stream>>>(adj, dist, a1p, d2p, d3p);
  hop2<<<B_ * L_ / 256, 256, 0, stream>>>(a1p, a2p);
  // qkv = x @ wqkv^T  (M=8192, N=2304, K=768)
  gemm_bt<0><<<dim3(3 * C_ / 128, B_ * L_ / 128), 256, 0, stream>>>(
      xbf, wqb, 3 * C_, C_, qb, kb, vTb, vb, nullptr);
  // attention: 4-wave blocks, 64 q-rows each
  attn_kernel<<<dim3(L_ / 64, BH_), 256, 0, stream>>>(qb, kb, vTb, vb, ob, a1p, a2p, d2p, d3p);
  // out = O @ wproj^T  (M=8192, N=768, K=768)
  gemm_bt<1><<<dim3(C_ / 128, B_ * L_ / 128), 256, 0, stream>>>(
      ob, wpb, C_, C_, nullptr, nullptr, nullptr, nullptr, out);
}

// Round 3
// 225.235 us; speedup vs baseline: 1.4322x; 1.0300x over previous
//
#include <hip/hip_runtime.h>

typedef unsigned short ushort_t;
typedef unsigned int uint_t;
typedef unsigned long long u64;
typedef __attribute__((ext_vector_type(8))) short bf16x8;
typedef __attribute__((ext_vector_type(4))) float f32x4;

#define B_ 8
#define L_ 1024
#define C_ 768
#define H_ 6
#define D_ 128
#define BH_ 48
#define NEGINF (-1e9f)

#define AS1 __attribute__((address_space(1)))
#define AS3 __attribute__((address_space(3)))

// round-to-nearest-even f32 -> bf16
__device__ __forceinline__ ushort_t f2bf(float f) {
  uint_t u = __builtin_bit_cast(uint_t, f);
  u += 0x7fffu + ((u >> 16) & 1u);
  return (ushort_t)(u >> 16);
}

// ---------------------------------------------------------------- converts
__global__ void cvt_f32_bf16(const float* __restrict__ in, ushort_t* __restrict__ out, int n8) {
  int i = blockIdx.x * 256 + threadIdx.x;
  if (i >= n8) return;
  const float4* p = (const float4*)in + (size_t)i * 2;
  float4 a = p[0], b = p[1];
  uint4 r;
  r.x = (uint_t)f2bf(a.x) | ((uint_t)f2bf(a.y) << 16);
  r.y = (uint_t)f2bf(a.z) | ((uint_t)f2bf(a.w) << 16);
  r.z = (uint_t)f2bf(b.x) | ((uint_t)f2bf(b.y) << 16);
  r.w = (uint_t)f2bf(b.z) | ((uint_t)f2bf(b.w) << 16);
  ((uint4*)out)[i] = r;
}

// ------------------------------------------------- bit-pack a1 / d<=2 / d<=3
__global__ __launch_bounds__(256)
void pack_masks(const int* __restrict__ adj, const int* __restrict__ dist,
                u64* __restrict__ a1p, u64* __restrict__ d2p, u64* __restrict__ d3p) {
  int l = blockIdx.x, b = blockIdx.y, t = threadIdx.x;
  size_t base = ((size_t)b * L_ + l) * L_;
  size_t rb = ((size_t)b * L_ + l) * 16;
  #pragma unroll
  for (int it = 0; it < 4; ++it) {
    int c = it * 256 + t;
    int av = adj[base + c];
    int dv = dist[base + c];
    u64 m1 = __ballot((av > 0) || (c == l));
    u64 m2 = __ballot(dv <= 2);
    u64 m3 = __ballot(dv <= 3);
    if ((t & 63) == 0) {
      int w = it * 4 + (t >> 6);
      a1p[rb + w] = m1; d2p[rb + w] = m2; d3p[rb + w] = m3;
    }
  }
}

// ------------------------------------------------- 2-hop closure (bit OR)
__global__ __launch_bounds__(256)
void hop2(const u64* __restrict__ a1p, u64* __restrict__ a2p) {
  int tid = blockIdx.x * 256 + threadIdx.x;   // 0..8191 = (b,l)
  int b = tid >> 10;
  size_t rb = (size_t)tid * 16;
  u64 row[16], acc[16];
  #pragma unroll
  for (int j = 0; j < 16; ++j) { row[j] = a1p[rb + j]; acc[j] = 0ULL; }
  bool done = false;
  #pragma unroll
  for (int mw = 0; mw < 16; ++mw) {
    if (done) continue;
    u64 bits = row[mw];
    while (bits) {
      int tz = __builtin_ctzll(bits); bits &= bits - 1;
      const u64* src = a1p + (((size_t)b << 10) + (mw << 6) + tz) * 16;
      u64 band = ~0ULL;
      #pragma unroll
      for (int j = 0; j < 16; ++j) { acc[j] |= src[j]; band &= acc[j]; }
      if (band == ~0ULL) { done = true; break; }
    }
  }
  #pragma unroll
  for (int j = 0; j < 16; ++j) a2p[rb + j] = acc[j];
}

// ------------------------------------------------- bf16 GEMM  C = A @ B^T
template<int EPI>
__global__ __launch_bounds__(256)
void gemm_bt(const ushort_t* __restrict__ A, const ushort_t* __restrict__ Bm,
             int N, int K,
             ushort_t* __restrict__ qo, ushort_t* __restrict__ ko,
             ushort_t* __restrict__ vTo, ushort_t* __restrict__ vo,
             float* __restrict__ fo) {
  __shared__ __align__(16) ushort_t As[128 * 32];
  __shared__ __align__(16) ushort_t Bs[128 * 32];
  int t = threadIdx.x;
  int lane = t & 63, lo = lane & 15, hi = lane >> 4;
  int wv = t >> 6, wm = wv >> 1, wn = wv & 1;
  int m0 = blockIdx.y * 128, n0 = blockIdx.x * 128;

  f32x4 acc[4][4];
  #pragma unroll
  for (int mi = 0; mi < 4; ++mi)
    #pragma unroll
    for (int ni = 0; ni < 4; ++ni) acc[mi][ni] = (f32x4){0.f, 0.f, 0.f, 0.f};

  for (int kt = 0; kt < K; kt += 32) {
    int u0 = t, u1 = t + 256;
    const ushort_t* ga0 = A + ((size_t)(m0 + (u0 >> 2)) * K + kt + (u0 & 3) * 8);
    const ushort_t* ga1 = A + ((size_t)(m0 + (u1 >> 2)) * K + kt + (u1 & 3) * 8);
    const ushort_t* gb0 = Bm + ((size_t)(n0 + (u0 >> 2)) * K + kt + (u0 & 3) * 8);
    const ushort_t* gb1 = Bm + ((size_t)(n0 + (u1 >> 2)) * K + kt + (u1 & 3) * 8);
    __builtin_amdgcn_global_load_lds((const AS1 void*)ga0, (AS3 void*)&As[(size_t)u0 * 8], 16, 0, 0);
    __builtin_amdgcn_global_load_lds((const AS1 void*)ga1, (AS3 void*)&As[(size_t)u1 * 8], 16, 0, 0);
    __builtin_amdgcn_global_load_lds((const AS1 void*)gb0, (AS3 void*)&Bs[(size_t)u0 * 8], 16, 0, 0);
    __builtin_amdgcn_global_load_lds((const AS1 void*)gb1, (AS3 void*)&Bs[(size_t)u1 * 8], 16, 0, 0);
    __syncthreads();
    bf16x8 af[4], bfr[4];
    #pragma unroll
    for (int mi = 0; mi < 4; ++mi)
      af[mi] = *(const bf16x8*)&As[(wm * 64 + mi * 16 + lo) * 32 + hi * 8];
    #pragma unroll
    for (int ni = 0; ni < 4; ++ni)
      bfr[ni] = *(const bf16x8*)&Bs[(wn * 64 + ni * 16 + lo) * 32 + hi * 8];
    #pragma unroll
    for (int mi = 0; mi < 4; ++mi)
      #pragma unroll
      for (int ni = 0; ni < 4; ++ni)
        acc[mi][ni] = __builtin_amdgcn_mfma_f32_16x16x32_bf16(af[mi], bfr[ni], acc[mi][ni], 0, 0, 0);
    __syncthreads();
  }

  // epilogue. D layout: col = lane&15, row = (lane>>4)*4 + j  [m89-verified]
  #pragma unroll
  for (int mi = 0; mi < 4; ++mi) {
    int rbase = m0 + wm * 64 + mi * 16 + hi * 4;
    #pragma unroll
    for (int ni = 0; ni < 4; ++ni) {
      int c = n0 + wn * 64 + ni * 16 + lo;
      f32x4 v = acc[mi][ni];
      if (EPI == 0) {
        int sec = c / 768;
        int cc = c - sec * 768;
        int h = cc >> 7, dd = cc & 127;
        #pragma unroll
        for (int j = 0; j < 4; ++j) {
          int r = rbase + j;
          int b = r >> 10, l = r & 1023;
          size_t bh = (size_t)(b * H_ + h);
          if (sec == 0)      qo[(bh * L_ + l) * D_ + dd] = f2bf(v[j] * 0.08838834764831845f);
          else if (sec == 1) ko[(bh * L_ + l) * D_ + dd] = f2bf(v[j]);
          else {
            ushort_t bv = f2bf(v[j]);
            vTo[(bh * D_ + dd) * L_ + l] = bv;
            vo[(bh * L_ + l) * D_ + dd] = bv;
          }
        }
      } else {
        #pragma unroll
        for (int j = 0; j < 4; ++j)
          fo[(size_t)(rbase + j) * N + c] = v[j];
      }
    }
  }
}

// ------------------------------------------------- flash attention w/ masks
// 4 waves / block; 64 q-rows per block. Double-buffered K/V staging (stage
// ch+1 before compute ch, one barrier per chunk) + mask register pipeline.
// grid = (bh, qt) so the 16 blocks sharing one bh pin to one XCD (48%8==0).
__global__ __launch_bounds__(256)
void attn_kernel(const ushort_t* __restrict__ q, const ushort_t* __restrict__ k,
                 const ushort_t* __restrict__ vT, const ushort_t* __restrict__ v,
                 ushort_t* __restrict__ obf,
                 const u64* __restrict__ a1p, const u64* __restrict__ a2p,
                 const u64* __restrict__ d2p, const u64* __restrict__ d3p) {
  __shared__ __align__(16) ushort_t Ks[2][64 * 128];   // [krow][d] swizzled 16B blocks
  __shared__ __align__(16) ushort_t Vs[2][128 * 64];   // [d][kcol] swizzled 16B blocks
  __shared__ __align__(16) ushort_t Plds[4][16 * 64];
  int t = threadIdx.x;
  int lane = t & 63, lo = lane & 15, hi = lane >> 4, wv = t >> 6;
  int bh = blockIdx.x, qt = blockIdx.y;
  int b = bh / H_, h = bh - b * H_;
  int qbase = qt * 64;          // block's q range
  int qw = qbase + wv * 16;     // this wave's q range

  if (h == 0) {
    // eye mask: softmax over the single diagonal element -> out = v[l]
    const ushort_t* vp0 = v + ((size_t)bh * L_ + qbase) * D_;
    #pragma unroll
    for (int it = 0; it < 4; ++it) {
      int r = it * 16 + (t >> 4);
      int cpos = (t & 15) * 8;
      bf16x8 val = *(const bf16x8*)(vp0 + (size_t)r * D_ + cpos);
      *(bf16x8*)(obf + ((size_t)b * L_ + qbase + r) * C_ + cpos) = val; // h*D_ == 0
    }
    return;
  }

  const ushort_t* qp = q + ((size_t)bh * L_ + qw) * D_;
  const ushort_t* kp = k + (size_t)bh * L_ * D_;
  const ushort_t* vp = vT + (size_t)bh * D_ * L_;

  bf16x8 aq[4];
  #pragma unroll
  for (int kk = 0; kk < 4; ++kk)
    aq[kk] = *(const bf16x8*)(qp + (size_t)lo * D_ + kk * 32 + hi * 8);

  const u64* mp = (h == 1) ? a1p : (h == 2) ? a2p : (h == 3) ? d2p : d3p;
  bool full = (h == 5);

  float m_run[4], l_run[4];
  f32x4 acc_o[8];
  #pragma unroll
  for (int j = 0; j < 4; ++j) { m_run[j] = NEGINF; l_run[j] = 0.f; }
  #pragma unroll
  for (int nt = 0; nt < 8; ++nt) acc_o[nt] = (f32x4){0.f, 0.f, 0.f, 0.f};

  // stage one K/V chunk into buffer `buf` (linear LDS dest, swizzled source)
  auto stage = [&](int buf, int ch) {
    int kc0 = ch * 64;
    #pragma unroll
    for (int i = 0; i < 4; ++i) {
      int u = i * 256 + t;
      int row = u >> 4, c16 = u & 15;
      int sc16 = c16 ^ (row & 7);
      __builtin_amdgcn_global_load_lds(
          (const AS1 void*)(kp + (size_t)(kc0 + row) * D_ + sc16 * 8),
          (AS3 void*)&Ks[buf][(size_t)u * 8], 16, 0, 0);
    }
    #pragma unroll
    for (int i = 0; i < 4; ++i) {
      int u = i * 256 + t;
      int row = u >> 3, c16 = u & 7;
      int sc16 = c16 ^ (row & 7);
      __builtin_amdgcn_global_load_lds(
          (const AS1 void*)(vp + (size_t)row * L_ + kc0 + sc16 * 8),
          (AS3 void*)&Vs[buf][(size_t)u * 8], 16, 0, 0);
    }
  };

  // prologue: stage chunk 0, load its mask words
  stage(0, 0);
  u64 wm_cur[4] = {0, 0, 0, 0};
  if (!full) {
    #pragma unroll
    for (int j = 0; j < 4; ++j)
      wm_cur[j] = mp[((size_t)b * L_ + qw + hi * 4 + j) * 16 + 0];
  }
  __syncthreads();   // drains vmcnt(0): chunk 0 staged

  for (int ch = 0; ch < 16; ++ch) {
    int cur = ch & 1;
    int kc0 = ch * 64;
    // issue next chunk's stage + mask prefetch BEFORE compute (latency hidden)
    if (ch < 15) stage(cur ^ 1, ch + 1);
    u64 wm_nxt[4] = {0, 0, 0, 0};
    if (!full && ch < 15) {
      #pragma unroll
      for (int j = 0; j < 4; ++j)
        wm_nxt[j] = mp[((size_t)b * L_ + qw + hi * 4 + j) * 16 + ch + 1];
    }

    const ushort_t* ks = &Ks[cur][0];
    const ushort_t* vs = &Vs[cur][0];

    // S tile: rows qw+hi*4+j, cols kc0 + st*16 + lo
    float sv[4][4];
    #pragma unroll
    for (int st = 0; st < 4; ++st) {
      f32x4 s = (f32x4){0.f, 0.f, 0.f, 0.f};
      int krow = st * 16 + lo;
      #pragma unroll
      for (int kk = 0; kk < 4; ++kk) {
        int c16s = (kk * 4 + hi) ^ (krow & 7);
        bf16x8 bk = *(const bf16x8*)&ks[krow * 128 + c16s * 8];
        s = __builtin_amdgcn_mfma_f32_16x16x32_bf16(aq[kk], bk, s, 0, 0, 0);
      }
      #pragma unroll
      for (int j = 0; j < 4; ++j) {
        bool bit = full || ((wm_cur[j] >> (st * 16 + lo)) & 1ULL);
        sv[st][j] = bit ? s[j] : NEGINF;
      }
    }
    (void)kc0;
    // online softmax per row j
    float corr[4], pv[4][4];
    #pragma unroll
    for (int j = 0; j < 4; ++j) {
      float mx = fmaxf(fmaxf(sv[0][j], sv[1][j]), fmaxf(sv[2][j], sv[3][j]));
      #pragma unroll
      for (int o = 8; o >= 1; o >>= 1) mx = fmaxf(mx, __shfl_xor(mx, o, 16));
      float mn = fmaxf(m_run[j], mx);
      corr[j] = __expf(m_run[j] - mn);
      float rs = 0.f;
      #pragma unroll
      for (int st = 0; st < 4; ++st) { float pp = __expf(sv[st][j] - mn); pv[st][j] = pp; rs += pp; }
      #pragma unroll
      for (int o = 8; o >= 1; o >>= 1) rs += __shfl_xor(rs, o, 16);
      l_run[j] = l_run[j] * corr[j] + rs;
      m_run[j] = mn;
    }
    f32x4 corrv = (f32x4){corr[0], corr[1], corr[2], corr[3]};
    #pragma unroll
    for (int nt = 0; nt < 8; ++nt) acc_o[nt] *= corrv;

    // P -> per-wave LDS (XOR-swizzled), then read back as A-frags
    char* pb = (char*)&Plds[wv][0];
    #pragma unroll
    for (int st = 0; st < 4; ++st)
      #pragma unroll
      for (int j = 0; j < 4; ++j) {
        int prow = hi * 4 + j;
        int addr = (prow * 128 + (st * 16 + lo) * 2) ^ ((prow & 7) << 4);
        *(ushort_t*)(pb + addr) = f2bf(pv[st][j]);
      }
    bf16x8 pa[2];
    #pragma unroll
    for (int kk2 = 0; kk2 < 2; ++kk2) {
      int addr = lo * 128 + (((kk2 * 4 + hi) ^ (lo & 7)) * 16);
      pa[kk2] = *(const bf16x8*)(pb + addr);
    }
    #pragma unroll
    for (int nt = 0; nt < 8; ++nt) {
      #pragma unroll
      for (int kk2 = 0; kk2 < 2; ++kk2) {
        int vrow = nt * 16 + lo;
        int c16s = (kk2 * 4 + hi) ^ (vrow & 7);
        bf16x8 bv = *(const bf16x8*)&vs[vrow * 64 + c16s * 8];
        acc_o[nt] = __builtin_amdgcn_mfma_f32_16x16x32_bf16(pa[kk2], bv, acc_o[nt], 0, 0, 0);
      }
    }
    // one barrier per chunk: drains this wave's stage loads (vmcnt(0)) and
    // LDS reads (lgkmcnt(0)) so buf[cur] may be overwritten next iteration.
    __syncthreads();
    wm_cur[0] = wm_nxt[0]; wm_cur[1] = wm_nxt[1];
    wm_cur[2] = wm_nxt[2]; wm_cur[3] = wm_nxt[3];
  }
  // epilogue
  float inv[4];
  #pragma unroll
  for (int j = 0; j < 4; ++j) inv[j] = 1.f / l_run[j];
  #pragma unroll
  for (int nt = 0; nt < 8; ++nt)
    #pragma unroll
    for (int j = 0; j < 4; ++j)
      obf[((size_t)b * L_ + qw + hi * 4 + j) * C_ + h * D_ + nt * 16 + lo] =
          f2bf(acc_o[nt][j] * inv[j]);
}

// ---------------------------------------------------------------- launcher
extern "C" void kernel_launch(void* const* d_in, const int* in_sizes, int n_in,
                              void* d_out, int out_size, void* d_ws, size_t ws_size,
                              hipStream_t stream) {
  const float* x     = (const float*)d_in[0];
  const int*   adj   = (const int*)d_in[1];
  const int*   dist  = (const int*)d_in[2];
  const float* wqkv  = (const float*)d_in[3];
  const float* wproj = (const float*)d_in[4];
  float* out = (float*)d_out;
  char* ws = (char*)d_ws;

  const size_t SZ_X   = (size_t)B_ * L_ * C_ * 2;        // 12.6 MB
  const size_t SZ_WQ  = (size_t)3 * C_ * C_ * 2;
  const size_t SZ_WP  = (size_t)C_ * C_ * 2;
  const size_t SZ_QKV = (size_t)BH_ * L_ * D_ * 2;       // 12.6 MB
  const size_t SZ_MSK = (size_t)B_ * L_ * 16 * 8;        // 1 MB
  size_t off = 0;
  ushort_t* xbf  = (ushort_t*)(ws + off); off += SZ_X;
  ushort_t* wqb  = (ushort_t*)(ws + off); off += SZ_WQ;
  ushort_t* wpb  = (ushort_t*)(ws + off); off += SZ_WP;
  ushort_t* qb   = (ushort_t*)(ws + off); off += SZ_QKV;
  ushort_t* kb   = (ushort_t*)(ws + off); off += SZ_QKV;
  ushort_t* vTb  = (ushort_t*)(ws + off); off += SZ_QKV;
  ushort_t* vb   = (ushort_t*)(ws + off); off += SZ_QKV;
  ushort_t* ob   = (ushort_t*)(ws + off); off += SZ_X;
  u64* a1p = (u64*)(ws + off); off += SZ_MSK;
  u64* a2p = (u64*)(ws + off); off += SZ_MSK;
  u64* d2p = (u64*)(ws + off); off += SZ_MSK;
  u64* d3p = (u64*)(ws + off); off += SZ_MSK;
  (void)ws_size; (void)n_in; (void)in_sizes; (void)out_size;

  cvt_f32_bf16<<<(B_ * L_ * C_ / 8 + 255) / 256, 256, 0, stream>>>(x, xbf, B_ * L_ * C_ / 8);
  cvt_f32_bf16<<<(3 * C_ * C_ / 8 + 255) / 256, 256, 0, stream>>>(wqkv, wqb, 3 * C_ * C_ / 8);
  cvt_f32_bf16<<<(C_ * C_ / 8 + 255) / 256, 256, 0, stream>>>(wproj, wpb, C_ * C_ / 8);
  pack_masks<<<dim3(L_, B_), 256, 0, stream>>>(adj, dist, a1p, d2p, d3p);
  hop2<<<B_ * L_ / 256, 256, 0, stream>>>(a1p, a2p);
  // qkv = x @ wqkv^T  (M=8192, N=2304, K=768)
  gemm_bt<0><<<dim3(3 * C_ / 128, B_ * L_ / 128), 256, 0, stream>>>(
      xbf, wqb, 3 * C_, C_, qb, kb, vTb, vb, nullptr);
  // attention: grid (bh, qt) for XCD pinning of each bh's K/V
  attn_kernel<<<dim3(BH_, L_ / 64), 256, 0, stream>>>(qb, kb, vTb, vb, ob, a1p, a2p, d2p, d3p);
  // out = O @ wproj^T  (M=8192, N=768, K=768)
  gemm_bt<1><<<dim3(C_ / 128, B_ * L_ / 128), 256, 0, stream>>>(
      ob, wpb, C_, C_, nullptr, nullptr, nullptr, nullptr, out);
}